// Round 3
// baseline (118.004 us; speedup 1.0000x reference)
//
#include <hip/hip_runtime.h>

#define B_   32
#define IN_  784
#define HID_ 256
#define OUT_ 128
#define MH_  32
#define RATE_ 1e-3f

// workspace layout (float offsets)
#define OFF_OUT1  0        // [32][256]  init vj1 by kA, accumulated by layer1
#define OFF_XT    8192     // [784][32]  x transposed
#define OFF_O1T   33280    // [256][32]  out1 transposed
#define OFF_VJ1T  41472    // [256][32]  vj1 transposed
#define OFF_VJ2T  49664    // [128][32]  vj2 transposed
// total 53760 floats = 215 KB

// ---------------- Kernel A: vj1 = relu(x @ W1^T + b1) -> out1, vjT1; xT = x^T
__global__ void kA(const float* __restrict__ x, const float* __restrict__ W1,
                   const float* __restrict__ b1, float* __restrict__ ws) {
    float* out1 = ws + OFF_OUT1;
    float* xT   = ws + OFF_XT;
    float* vjT1 = ws + OFF_VJ1T;
    int t = threadIdx.x, blk = blockIdx.x;

    if (blk < 98) {                     // transpose x: 25088 elements
        int e = blk * 256 + t;          // e = i*32 + b
        int i = e >> 5, b = e & 31;
        xT[e] = x[b * IN_ + i];
    }

    int lane = t & 63;
    int p = blk * 4 + (t >> 6);         // pair index < 8192
    int b = p >> 8, o = p & 255;
    const float4* xr4 = (const float4*)(x  + b * IN_);
    const float4* wr4 = (const float4*)(W1 + o * IN_);
    float acc = 0.f;
    #pragma unroll
    for (int k = 0; k < 3; ++k) {       // 3*64 = 192 float4 = 768 elements
        float4 xa = xr4[lane + 64 * k];
        float4 wa = wr4[lane + 64 * k];
        acc = fmaf(xa.x, wa.x, acc); acc = fmaf(xa.y, wa.y, acc);
        acc = fmaf(xa.z, wa.z, acc); acc = fmaf(xa.w, wa.w, acc);
    }
    if (lane < 4) {                     // tail: elements 768..783
        float4 xa = xr4[192 + lane];
        float4 wa = wr4[192 + lane];
        acc = fmaf(xa.x, wa.x, acc); acc = fmaf(xa.y, wa.y, acc);
        acc = fmaf(xa.z, wa.z, acc); acc = fmaf(xa.w, wa.w, acc);
    }
    #pragma unroll
    for (int m = 1; m < 64; m <<= 1) acc += __shfl_xor(acc, m, 64);
    if (lane == 0) {
        float v = fmaxf(acc + b1[o], 0.f);
        out1[p] = v;                    // out1[b][o] = vj1
        vjT1[o * 32 + b] = v;
    }
}

// ---------------- Layer main ----------------
// Each thread owns ONE i (its lane) and loops all 32 b in registers.
// Meta params + vjT[o][*] are wave-uniform -> SGPR (scalar pipe).
// W_new mean over b is a thread-local sum (no shuffles).
// out-acc reduced over i once per block via padded LDS.
template<int IN_DIM, int OUT_DIM, int NCH, int IBLK>
__global__ __launch_bounds__(128)
void layer_main(const float* __restrict__ viT,   // [IN_DIM][32]
                const float* __restrict__ W,     // [OUT_DIM][IN_DIM]
                const float* __restrict__ vjT,   // [OUT_DIM][32]
                const float* __restrict__ mW1, const float* __restrict__ mb1,
                const float* __restrict__ mW2, const float* __restrict__ mb2,
                const int*   __restrict__ batch_num,
                float* __restrict__ Wnew,        // [OUT_DIM][IN_DIM]
                float* __restrict__ outAcc)      // [32][OUT_DIM]
{
    __shared__ float osh[32 * 129];              // [b][i] padded: bank = (b+i)%32
    __shared__ float psh[128];

    int t = threadIdx.x;
    int o  = blockIdx.x / NCH;
    int il = t;
    bool act = (IBLK == 128) || (il < IBLK);
    int i = (blockIdx.x % NCH) * IBLK + (act ? il : 0);

    float wv = act ? W[o * IN_DIM + i] : 0.f;

    // vi[b] for this i (zeros for inactive threads -> their outacc contributions = 0)
    float vi[32];
    {
        const float4* vp = (const float4*)(viT + i * 32);
        #pragma unroll
        for (int k = 0; k < 8; ++k) {
            float4 v4 = act ? vp[k] : make_float4(0.f, 0.f, 0.f, 0.f);
            vi[4*k+0] = v4.x; vi[4*k+1] = v4.y; vi[4*k+2] = v4.z; vi[4*k+3] = v4.w;
        }
    }

    // vj[b] for this o: wave-uniform -> scalar loads
    float vjv[32];
    {
        const float* vp = vjT + o * 32;
        #pragma unroll
        for (int k = 0; k < 32; ++k) vjv[k] = vp[k];
    }

    float s[32];
    #pragma unroll
    for (int k = 0; k < 32; ++k) s[k] = 0.f;

    #pragma unroll 8
    for (int h = 0; h < MH_; ++h) {
        float a  = mW1[3*h + 0];
        float bw = mW1[3*h + 1];
        float c  = mW1[3*h + 2];
        float w2 = mW2[h];
        float base = fmaf(bw, wv, mb1[h]);       // hoisted over b
        #pragma unroll
        for (int bb = 0; bb < 32; ++bb) {
            float pre = fmaf(c, vjv[bb], base);
            float tt  = fmaf(a, vi[bb], pre);
            tt = fmaxf(tt, 0.f);
            s[bb] = fmaf(w2, tt, s[bb]);
        }
    }

    float scale = RATE_ / (float)batch_num[0];
    float mb2v  = mb2[0];
    float wsum = 0.f;
    #pragma unroll
    for (int bb = 0; bb < 32; ++bb) {
        float sh = (s[bb] + mb2v) * scale;
        wsum += sh;
        osh[bb * 129 + t] = vi[bb] * sh;         // bank-safe: (b*129+t)%32 = (b+t)%32
    }
    if (act) Wnew[o * IN_DIM + i] = wv + wsum * 0.03125f;

    __syncthreads();
    {   // stage 1: 128 threads, each sums 32 i's for one (b, seg)
        int b = t & 31, seg = t >> 5;
        const float* row = osh + b * 129 + seg * 32;
        float p = 0.f;
        #pragma unroll
        for (int k = 0; k < 32; ++k) p += row[k];
        psh[t] = p;
    }
    __syncthreads();
    if (t < 32) {
        float v = psh[t] + psh[32 + t] + psh[64 + t] + psh[96 + t];
        atomicAdd(&outAcc[t * OUT_DIM + o], v);
    }
}

// ---------------- Kernel C: vj2 = relu(out1 @ W2^T + b2) -> out2, vj2T; o1T
__global__ void kC(const float* __restrict__ out1, const float* __restrict__ W2,
                   const float* __restrict__ b2, float* __restrict__ vj2T,
                   float* __restrict__ o1T, float* __restrict__ out2) {
    int t = threadIdx.x, blk = blockIdx.x;

    if (blk < 32) {                     // transpose out1: 8192 elements
        int e = blk * 256 + t;
        int i = e >> 5, b = e & 31;
        o1T[e] = out1[b * HID_ + i];
    }

    int lane = t & 63;
    int p = blk * 4 + (t >> 6);         // pair < 4096
    int b = p >> 7, o = p & 127;
    const float4* xr4 = (const float4*)(out1 + b * HID_);
    const float4* wr4 = (const float4*)(W2   + b * 0 + o * HID_);
    float4 xa = xr4[lane];              // 64 lanes * 4 = 256 elements exactly
    float4 wa = wr4[lane];
    float acc = fmaf(xa.x, wa.x, fmaf(xa.y, wa.y, fmaf(xa.z, wa.z, xa.w * wa.w)));
    #pragma unroll
    for (int m = 1; m < 64; m <<= 1) acc += __shfl_xor(acc, m, 64);
    if (lane == 0) {
        float v = fmaxf(acc + b2[o], 0.f);
        out2[p]          = v;           // out2[b][o] init = vj2
        vj2T[o * 32 + b] = v;
    }
}

extern "C" void kernel_launch(void* const* d_in, const int* in_sizes, int n_in,
                              void* d_out, int out_size, void* d_ws, size_t ws_size,
                              hipStream_t stream) {
    const float* x   = (const float*)d_in[0];
    const float* W1  = (const float*)d_in[1];
    const float* b1  = (const float*)d_in[2];
    const float* W2  = (const float*)d_in[3];
    const float* b2  = (const float*)d_in[4];
    const float* mW1 = (const float*)d_in[5];
    const float* mb1 = (const float*)d_in[6];
    const float* mW2 = (const float*)d_in[7];
    const float* mb2 = (const float*)d_in[8];
    const int* batch_num = (const int*)d_in[9];

    float* out2  = (float*)d_out;               // [32*128]
    float* W1n   = out2 + B_ * OUT_;            // [256*784]
    float* W2n   = W1n + HID_ * IN_;            // [128*256]
    float* ws    = (float*)d_ws;

    // A: vj1 (-> out1, vjT1) + xT
    kA<<<2048, 256, 0, stream>>>(x, W1, b1, ws);
    // B: layer 1 main — 256 o * 7 chunks of 112 i, 128 threads (112 active)
    layer_main<IN_, HID_, 7, 112><<<HID_ * 7, 128, 0, stream>>>(
        ws + OFF_XT, W1, ws + OFF_VJ1T, mW1, mb1, mW2, mb2, batch_num,
        W1n, ws + OFF_OUT1);
    // C: vj2 (-> out2, vj2T) + o1T
    kC<<<1024, 256, 0, stream>>>(ws + OFF_OUT1, W2, b2,
                                 ws + OFF_VJ2T, ws + OFF_O1T, out2);
    // D: layer 2 main — 128 o * 2 chunks of 128 i
    layer_main<HID_, OUT_, 2, 128><<<OUT_ * 2, 128, 0, stream>>>(
        ws + OFF_O1T, W2, ws + OFF_VJ2T, mW1, mb1, mW2, mb2, batch_num,
        W2n, out2);
}

// Round 4
// 110.774 us; speedup vs baseline: 1.0653x; 1.0653x over previous
//
#include <hip/hip_runtime.h>

#define B_   32
#define IN_  784
#define HID_ 256
#define OUT_ 128
#define MH_  32
#define RATE_ 1e-3f

// workspace layout (float offsets)
#define OFF_OUT1  0        // [32][256]  init vj1 by kA, accumulated by layer1
#define OFF_XT    8192     // [784][32]  x transposed
#define OFF_O1T   33280    // [256][32]  out1 transposed
#define OFF_VJ1T  41472    // [256][32]  vj1 transposed
#define OFF_VJ2T  49664    // [128][32]  vj2 transposed

// ---------------- Kernel A: vj1 = relu(x @ W1^T + b1) -> out1, vjT1; xT = x^T
__global__ void kA(const float* __restrict__ x, const float* __restrict__ W1,
                   const float* __restrict__ b1, float* __restrict__ ws) {
    float* out1 = ws + OFF_OUT1;
    float* xT   = ws + OFF_XT;
    float* vjT1 = ws + OFF_VJ1T;
    int t = threadIdx.x, blk = blockIdx.x;

    if (blk < 98) {                     // transpose x: 25088 elements
        int e = blk * 256 + t;          // e = i*32 + b
        int i = e >> 5, b = e & 31;
        xT[e] = x[b * IN_ + i];
    }

    int lane = t & 63;
    int p = blk * 4 + (t >> 6);         // pair index < 8192
    int b = p >> 8, o = p & 255;
    const float4* xr4 = (const float4*)(x  + b * IN_);
    const float4* wr4 = (const float4*)(W1 + o * IN_);
    float acc = 0.f;
    #pragma unroll
    for (int k = 0; k < 3; ++k) {       // 3*64 = 192 float4 = 768 elements
        float4 xa = xr4[lane + 64 * k];
        float4 wa = wr4[lane + 64 * k];
        acc = fmaf(xa.x, wa.x, acc); acc = fmaf(xa.y, wa.y, acc);
        acc = fmaf(xa.z, wa.z, acc); acc = fmaf(xa.w, wa.w, acc);
    }
    if (lane < 4) {                     // tail: elements 768..783
        float4 xa = xr4[192 + lane];
        float4 wa = wr4[192 + lane];
        acc = fmaf(xa.x, wa.x, acc); acc = fmaf(xa.y, wa.y, acc);
        acc = fmaf(xa.z, wa.z, acc); acc = fmaf(xa.w, wa.w, acc);
    }
    #pragma unroll
    for (int m = 1; m < 64; m <<= 1) acc += __shfl_xor(acc, m, 64);
    if (lane == 0) {
        float v = fmaxf(acc + b1[o], 0.f);
        out1[p] = v;                    // out1[b][o] = vj1
        vjT1[o * 32 + b] = v;
    }
}

// ---------------- Layer main ----------------
// Thread layout: t = b + 32*g. Half-wave (32 b-lanes) owns CPT contiguous i's.
// Loop nest: h-chunks of 8 OUTER (params LDS->regs once per chunk, cvm=c*vj+mb1
// hoisted per chunk), i INNER over register-resident s[CPT]/vi[CPT]/wv[CPT].
// Inner eval = fma + fma + max + fma (4 ops) -> VALU-bound by construction.
template<int IN_DIM, int OUT_DIM, int NCH, int CPT>
__global__ __launch_bounds__(256)
void layer_main(const float* __restrict__ viT,   // [IN_DIM][32]
                const float* __restrict__ W,     // [OUT_DIM][IN_DIM]
                const float* __restrict__ vjT,   // [OUT_DIM][32]
                const float* __restrict__ mW1, const float* __restrict__ mb1,
                const float* __restrict__ mW2, const float* __restrict__ mb2,
                const int*   __restrict__ batch_num,
                float* __restrict__ Wnew,        // [OUT_DIM][IN_DIM]
                float* __restrict__ outAcc)      // [32][OUT_DIM]
{
    __shared__ float4 m4s[MH_];                  // {a, bw, c, mb1}
    __shared__ float  w2s[MH_];
    __shared__ float  osh[4][32];

    int t = threadIdx.x;
    int b = t & 31, g = t >> 5;
    int o  = blockIdx.x / NCH;
    int i0 = (blockIdx.x % NCH) * (8 * CPT) + g * CPT;

    if (t < MH_) {
        m4s[t] = make_float4(mW1[t*3+0], mW1[t*3+1], mW1[t*3+2], mb1[t]);
        w2s[t] = mW2[t];
    }
    __syncthreads();

    float vjv = vjT[o * 32 + b];

    float vi[CPT], wv[CPT], s[CPT];
    #pragma unroll
    for (int k = 0; k < CPT; ++k) {
        vi[k] = viT[(i0 + k) * 32 + b];          // coalesced per half-wave
        wv[k] = W[o * IN_DIM + i0 + k];          // uniform per half-wave (broadcast)
        s[k]  = 0.f;
    }

    #pragma unroll
    for (int hc = 0; hc < MH_ / 8; ++hc) {
        float a[8], bw[8], w2[8], cvm[8];
        #pragma unroll
        for (int j = 0; j < 8; ++j) {
            float4 m = m4s[hc * 8 + j];          // LDS broadcast, once per 8*CPT evals
            a[j]   = m.x;
            bw[j]  = m.y;
            cvm[j] = fmaf(m.z, vjv, m.w);        // c*vj + mb1, hoisted over i
            w2[j]  = w2s[hc * 8 + j];
        }
        #pragma unroll
        for (int k = 0; k < CPT; ++k) {
            float vik = vi[k], wvk = wv[k];
            #pragma unroll
            for (int j = 0; j < 8; ++j) {
                float tt = fmaf(a[j], vik, fmaf(bw[j], wvk, cvm[j]));
                tt = fmaxf(tt, 0.f);
                s[k] = fmaf(w2[j], tt, s[k]);
            }
        }
    }

    float scale = RATE_ / (float)batch_num[0];
    float mb2v  = mb2[0];
    float outacc = 0.f;
    float r[CPT];
    #pragma unroll
    for (int k = 0; k < CPT; ++k) {
        float sh = (s[k] + mb2v) * scale;
        outacc = fmaf(vi[k], sh, outacc);
        r[k] = sh;
    }
    // reduce r[k] over the 32 b-lanes of each half-wave
    #pragma unroll
    for (int mm = 1; mm < 32; mm <<= 1) {
        #pragma unroll
        for (int k = 0; k < CPT; ++k) r[k] += __shfl_xor(r[k], mm);
    }
    if (b == 0) {
        #pragma unroll
        for (int k = 0; k < CPT; ++k)
            Wnew[o * IN_DIM + i0 + k] = wv[k] + r[k] * 0.03125f;
    }

    // reduce outacc over the 8 half-waves
    outacc += __shfl_xor(outacc, 32);
    if ((t & 32) == 0) osh[t >> 6][b] = outacc;
    __syncthreads();
    if (t < 32) {
        float v = osh[0][t] + osh[1][t] + osh[2][t] + osh[3][t];
        atomicAdd(&outAcc[t * OUT_DIM + o], v);
    }
}

// ---------------- Kernel C: vj2 = relu(out1 @ W2^T + b2) -> out2, vj2T; o1T
__global__ void kC(const float* __restrict__ out1, const float* __restrict__ W2,
                   const float* __restrict__ b2, float* __restrict__ vj2T,
                   float* __restrict__ o1T, float* __restrict__ out2) {
    int t = threadIdx.x, blk = blockIdx.x;

    if (blk < 32) {                     // transpose out1: 8192 elements
        int e = blk * 256 + t;
        int i = e >> 5, b = e & 31;
        o1T[e] = out1[b * HID_ + i];
    }

    int lane = t & 63;
    int p = blk * 4 + (t >> 6);         // pair < 4096
    int b = p >> 7, o = p & 127;
    const float4* xr4 = (const float4*)(out1 + b * HID_);
    const float4* wr4 = (const float4*)(W2   + o * HID_);
    float4 xa = xr4[lane];              // 64 lanes * 4 = 256 elements exactly
    float4 wa = wr4[lane];
    float acc = fmaf(xa.x, wa.x, fmaf(xa.y, wa.y, fmaf(xa.z, wa.z, xa.w * wa.w)));
    #pragma unroll
    for (int m = 1; m < 64; m <<= 1) acc += __shfl_xor(acc, m, 64);
    if (lane == 0) {
        float v = fmaxf(acc + b2[o], 0.f);
        out2[p]          = v;           // out2[b][o] init = vj2
        vj2T[o * 32 + b] = v;
    }
}

extern "C" void kernel_launch(void* const* d_in, const int* in_sizes, int n_in,
                              void* d_out, int out_size, void* d_ws, size_t ws_size,
                              hipStream_t stream) {
    const float* x   = (const float*)d_in[0];
    const float* W1  = (const float*)d_in[1];
    const float* b1  = (const float*)d_in[2];
    const float* W2  = (const float*)d_in[3];
    const float* b2  = (const float*)d_in[4];
    const float* mW1 = (const float*)d_in[5];
    const float* mb1 = (const float*)d_in[6];
    const float* mW2 = (const float*)d_in[7];
    const float* mb2 = (const float*)d_in[8];
    const int* batch_num = (const int*)d_in[9];

    float* out2  = (float*)d_out;               // [32*128]
    float* W1n   = out2 + B_ * OUT_;            // [256*784]
    float* W2n   = W1n + HID_ * IN_;            // [128*256]
    float* ws    = (float*)d_ws;

    // A: vj1 (-> out1, vjT1) + xT
    kA<<<2048, 256, 0, stream>>>(x, W1, b1, ws);
    // B: layer 1 main — 256 o * 7 chunks; 8 half-waves * CPT=14 i = 112 i/block
    layer_main<IN_, HID_, 7, 14><<<HID_ * 7, 256, 0, stream>>>(
        ws + OFF_XT, W1, ws + OFF_VJ1T, mW1, mb1, mW2, mb2, batch_num,
        W1n, ws + OFF_OUT1);
    // C: vj2 (-> out2, vj2T) + o1T
    kC<<<1024, 256, 0, stream>>>(ws + OFF_OUT1, W2, b2,
                                 ws + OFF_VJ2T, ws + OFF_O1T, out2);
    // D: layer 2 main — 128 o * 8 chunks; 8 half-waves * CPT=4 i = 32 i/block
    layer_main<HID_, OUT_, 8, 4><<<OUT_ * 8, 256, 0, stream>>>(
        ws + OFF_O1T, W2, ws + OFF_VJ2T, mW1, mb1, mW2, mb2, batch_num,
        W2n, out2);
}